// Round 8
// baseline (355.042 us; speedup 1.0000x reference)
//
#include <hip/hip_runtime.h>
#include <hip/hip_fp16.h>
#include <stdint.h>

// AgreementRouting round 8: R7 (fp16-copy) structure, restructured memory:
// each lane loads 5x16B uint4 chunks per row (4 lanes = full 64B sectors),
// halving vector-mem instructions; dot needs shfl_xor(1)+xor(2) only (DPP).
// Explicit 2-deep load pipeline over the fully-unrolled 9-step loop.
// Theory: R1/R2/R6/R7 all cap at ~4 TB/s logical independent of occupancy
// (R2: 32 waves/CU) and coalescing (R6: DMA) -> per-CU issue/serialization;
// fewer, wider, pipelined loads attack that directly.
// u[B=32][G=8][S=1152][O=10][D=16] f32, b_param[G][1][S][O] f32.
#define NB 32
#define NG 8
#define NS 1152
#define NO 10
#define ND 16
#define EPSV 1e-8f

#define THREADS 512
#define NSTEPS 9               // 128 rows per step, 4 lanes per row

typedef float f4v __attribute__((ext_vector_type(4)));

__global__ __launch_bounds__(THREADS)
void AgreementRouting_72988674228343_kernel(const float* __restrict__ u,
                                            const float* __restrict__ bparam,
                                            const int* __restrict__ n_iter_p,
                                            float* __restrict__ out,
                                            uint4* __restrict__ uh)
{
    __shared__ float b_lds[NS * NO];      // 45 KB constant b_param slice
    __shared__ float sredl[8][4][5][8];   // per-wave partials: [wave][j][k][i]
    __shared__ float v_lds[NO * ND];      // vcum = sum of v_j so far

    const int tid  = threadIdx.x;
    const int bg   = blockIdx.x;          // b*8 + g
    const int g    = bg & 7;
    const int bb   = bg >> 3;
    const int wave = tid >> 6;
    const int lane = tid & 63;
    const int j    = tid & 3;             // quad lane
    const int rl   = tid >> 2;            // row within step (0..127)
    const int half8 = j & 1;              // d-half (8 floats)
    const int par   = j >> 1;             // o parity: lane owns o = 2k+par

    const int n = n_iter_p[0];

    const float* bp = bparam + (size_t)g * (NS * NO);
    for (int i = tid; i < NS * NO; i += THREADS) b_lds[i] = bp[i];
    if (tid < NO * ND) v_lds[tid] = 0.f;

    const f4v* u4  = (const f4v*)u + (size_t)bg * (NS * 40);  // 40 float4/row
    uint4*     uh4 = uh + (size_t)bg * (NS * 20);             // 20 uint4/row

    __syncthreads();

    for (int r = 0; r < n; ++r) {
        float sacc[5][8];
#pragma unroll
        for (int k = 0; k < 5; ++k)
#pragma unroll
            for (int i = 0; i < 8; ++i) sacc[k][i] = 0.f;

        if (r == 0) {
            // fp32 pass: exact compute + write fp16 copy
            for (int step = 0; step < NSTEPS; ++step) {
                const int s = step * 128 + rl;
                float uf[5][8];
#pragma unroll
                for (int k = 0; k < 5; ++k) {
                    const int f = k * 4 + j;            // chunk index in row
                    const f4v a = __builtin_nontemporal_load(u4 + (size_t)s * 40 + f * 2);
                    const f4v b = __builtin_nontemporal_load(u4 + (size_t)s * 40 + f * 2 + 1);
                    uf[k][0] = a.x; uf[k][1] = a.y; uf[k][2] = a.z; uf[k][3] = a.w;
                    uf[k][4] = b.x; uf[k][5] = b.y; uf[k][6] = b.z; uf[k][7] = b.w;
                    if (n > 1) {
                        uint4 pk;
                        pk.x = __builtin_bit_cast(uint32_t, __floats2half2_rn(a.x, a.y));
                        pk.y = __builtin_bit_cast(uint32_t, __floats2half2_rn(a.z, a.w));
                        pk.z = __builtin_bit_cast(uint32_t, __floats2half2_rn(b.x, b.y));
                        pk.w = __builtin_bit_cast(uint32_t, __floats2half2_rn(b.z, b.w));
                        uh4[(size_t)s * 20 + f] = pk;
                    }
                }
                float bn[NO];
#pragma unroll
                for (int o = 0; o < NO; ++o) bn[o] = b_lds[s * NO + o];
                float mx = bn[0];
#pragma unroll
                for (int o = 1; o < NO; ++o) mx = fmaxf(mx, bn[o]);
                float ss = 0.f;
#pragma unroll
                for (int o = 0; o < NO; ++o) { bn[o] = __expf(bn[o] - mx); ss += bn[o]; }
                const float inv = 1.f / ss;
#pragma unroll
                for (int k = 0; k < 5; ++k) {
                    const float c = bn[2 * k + par] * inv;
#pragma unroll
                    for (int i = 0; i < 8; ++i) sacc[k][i] += c * uf[k][i];
                }
            }
        } else {
            // fp16 passes: lane's vcum chunks cached in registers
            float vc[5][8];
#pragma unroll
            for (int k = 0; k < 5; ++k) {
                const int o = 2 * k + par;
#pragma unroll
                for (int i = 0; i < 8; ++i) vc[k][i] = v_lds[o * ND + half8 * 8 + i];
            }

            uint4 ld[2][5];
#pragma unroll
            for (int k = 0; k < 5; ++k)
                ld[0][k] = uh4[(size_t)rl * 20 + k * 4 + j];   // step 0 prologue

#pragma unroll
            for (int step = 0; step < NSTEPS; ++step) {
                const int cur = step & 1;                      // static under unroll
                if (step + 1 < NSTEPS) {
                    const int s2 = (step + 1) * 128 + rl;
#pragma unroll
                    for (int k = 0; k < 5; ++k)
                        ld[cur ^ 1][k] = uh4[(size_t)s2 * 20 + k * 4 + j];
                }
                const int s = step * 128 + rl;
                float uf[5][8];
#pragma unroll
                for (int k = 0; k < 5; ++k) {
                    const float2 p0 = __half22float2(__builtin_bit_cast(__half2, ld[cur][k].x));
                    const float2 p1 = __half22float2(__builtin_bit_cast(__half2, ld[cur][k].y));
                    const float2 p2 = __half22float2(__builtin_bit_cast(__half2, ld[cur][k].z));
                    const float2 p3 = __half22float2(__builtin_bit_cast(__half2, ld[cur][k].w));
                    uf[k][0] = p0.x; uf[k][1] = p0.y; uf[k][2] = p1.x; uf[k][3] = p1.y;
                    uf[k][4] = p2.x; uf[k][5] = p2.y; uf[k][6] = p3.x; uf[k][7] = p3.y;
                }
                float bo[5], bx[5];
#pragma unroll
                for (int k = 0; k < 5; ++k) {
                    float p = 0.f;
#pragma unroll
                    for (int i = 0; i < 8; ++i) p += uf[k][i] * vc[k][i];
                    p += __shfl_xor(p, 1);                 // other d-half (DPP)
                    bo[k] = b_lds[s * NO + 2 * k + par] + p;
                    bx[k] = __shfl_xor(bo[k], 2);          // other o-parity (DPP)
                }
                // softmax over all 10 logits (own 5 + partner 5)
                float mx = fmaxf(bo[0], bx[0]);
#pragma unroll
                for (int k = 1; k < 5; ++k) mx = fmaxf(mx, fmaxf(bo[k], bx[k]));
                float ss = 0.f;
                float eo[5];
#pragma unroll
                for (int k = 0; k < 5; ++k) {
                    eo[k] = __expf(bo[k] - mx);
                    ss += eo[k] + __expf(bx[k] - mx);
                }
                const float inv = 1.f / ss;
#pragma unroll
                for (int k = 0; k < 5; ++k) {
                    const float c = eo[k] * inv;
#pragma unroll
                    for (int i = 0; i < 8; ++i) sacc[k][i] += c * uf[k][i];
                }
            }
        }

        // reduce over the 16 quads of each wave (masks 4..32 preserve j)
#pragma unroll
        for (int k = 0; k < 5; ++k)
#pragma unroll
            for (int i = 0; i < 8; ++i) {
#pragma unroll
                for (int mask = 4; mask <= 32; mask <<= 1)
                    sacc[k][i] += __shfl_xor(sacc[k][i], mask);
            }
        if (lane < 4) {
#pragma unroll
            for (int k = 0; k < 5; ++k)
#pragma unroll
                for (int i = 0; i < 8; ++i) sredl[wave][lane][k][i] = sacc[k][i];
        }
        __syncthreads();

        if (tid < NO * ND) {               // 160 threads: (o, d)
            const int o = tid >> 4, d = tid & 15;
            const int jj = (o & 1) * 2 + (d >> 3);
            const int k  = o >> 1, i = d & 7;
            float s = sredl[0][jj][k][i];
#pragma unroll
            for (int w = 1; w < 8; ++w) s += sredl[w][jj][k][i];
            // squash: v = s*(|s|^2/(1+|s|^2))/(|s|+eps); norm over 16 d-lanes
            float q = s * s;
            q += __shfl_xor(q, 1); q += __shfl_xor(q, 2);
            q += __shfl_xor(q, 4); q += __shfl_xor(q, 8);
            const float len = sqrtf(q);
            const float f = (q / (1.f + q)) / (len + EPSV);
            const float v = s * f;
            v_lds[tid] += v;               // vcum for next pass
            if (r == n - 1)
                atomicAdd(&out[(size_t)bb * (NO * ND) + tid], v);  // sum over g
        }
        __syncthreads();                   // vcum visible before next pass
    }
}

extern "C" void kernel_launch(void* const* d_in, const int* in_sizes, int n_in,
                              void* d_out, int out_size, void* d_ws, size_t ws_size,
                              hipStream_t stream) {
    const float* u   = (const float*)d_in[0];
    const float* bp  = (const float*)d_in[1];
    const int*   nit = (const int*)d_in[2];
    float* out = (float*)d_out;
    uint4* uh  = (uint4*)d_ws;             // fp16 copy of u: 94.4 MB

    hipMemsetAsync(out, 0, (size_t)out_size * sizeof(float), stream);

    AgreementRouting_72988674228343_kernel<<<dim3(NB * NG), dim3(THREADS), 0, stream>>>(
        u, bp, nit, out, uh);
}

// Round 15
// 314.580 us; speedup vs baseline: 1.1286x; 1.1286x over previous
//
#include <hip/hip_runtime.h>
#include <hip/hip_fp16.h>
#include <stdint.h>

// AgreementRouting round 15: exact resubmission of the round-7 champion
// (passed: dur_us 313.2, kernel 117us, absmax 0.0078, 64 VGPR, no spills).
// R13/R14 were lost to GPU acquisition timeouts; nothing new to incorporate.
// The THREADS=1024 variants (R10/R12) produced bit-identical wrong output
// regardless of nt hints -> logical bug in that restructure; abandoned.
// Structure: one block per (b,g), 512 threads; pass 0 reads u fp32 once
// (nontemporal) and writes an fp16 copy to d_ws; passes 1-2 read fp16.
// Linearity (R2-validated): logits_r = b_param + dot(u, sum_{j<r} v_j);
// LDS carries the constant b_param slice + cumulative vcum. Byte floor:
// 189 MB fp32 read + 93 MB fp16 write + 2x94.5 MB fp16 reads = 470 MB at
// the ~4.0-4.3 TB/s empirically-established service ceiling for this mix.
// u[B=32][G=8][S=1152][O=10][D=16] f32, b_param[G][1][S][O] f32.
#define NB 32
#define NG 8
#define NS 1152
#define NO 10
#define ND 16
#define EPSV 1e-8f

#define THREADS 512
#define GRPS (THREADS / 4)     // 128 s-rows per step (4 lanes per row)
#define NSTEPS (NS / GRPS)     // 9
#define UHROW (NO * 4)         // uint2 chunks per row in fp16 copy (40)

typedef float f4v __attribute__((ext_vector_type(4)));

__global__ __launch_bounds__(THREADS)
void AgreementRouting_72988674228343_kernel(const float* __restrict__ u,
                                            const float* __restrict__ bparam,
                                            const int* __restrict__ n_iter_p,
                                            float* __restrict__ out,
                                            uint2* __restrict__ uh)
{
    __shared__ float  b_lds[NS * NO];    // 45 KB constant b_param slice
    __shared__ float4 sred[8][NO][4];    // per-wave partial s-sums
    __shared__ float4 v_lds[NO][4];      // vcum = sum of v_j so far

    const int tid  = threadIdx.x;
    const int bg   = blockIdx.x;         // b*8 + g
    const int g    = bg & 7;
    const int bb   = bg >> 3;
    const int wave = tid >> 6;
    const int lane = tid & 63;
    const int d4   = tid & 3;            // float4 chunk of D
    const int grp  = tid >> 2;           // s-row group (0..127)

    const int n = n_iter_p[0];

    const float* bp = bparam + (size_t)g * (NS * NO);
    for (int i = tid; i < NS * NO; i += THREADS) b_lds[i] = bp[i];
    if (tid < NO * 4) v_lds[tid >> 2][tid & 3] = make_float4(0.f, 0.f, 0.f, 0.f);

    const f4v* ub  = (const f4v*)u + (size_t)bg * (NS * NO * 4);
    uint2*     uhb = uh + (size_t)bg * (NS * UHROW);

    __syncthreads();

    for (int r = 0; r < n; ++r) {
        float4 sacc[NO];
#pragma unroll
        for (int o = 0; o < NO; ++o) sacc[o] = make_float4(0.f, 0.f, 0.f, 0.f);

        for (int step = 0; step < NSTEPS; ++step) {
            const int s = step * GRPS + grp;
            float4 uu[NO];
            float bnew[NO];

            if (r == 0) {
                // fp32 read (nontemporal: consumed once, keep L3 for fp16 copy)
                const f4v* row = ub + (size_t)s * (NO * 4) + d4;
                f4v t[NO];
#pragma unroll
                for (int o = 0; o < NO; ++o) t[o] = __builtin_nontemporal_load(row + o * 4);
                if (n > 1) {               // write fp16 copy for passes 1..n-1
                    uint2* wrow = uhb + (size_t)s * UHROW + d4;
#pragma unroll
                    for (int o = 0; o < NO; ++o) {
                        const __half2 lo = __floats2half2_rn(t[o].x, t[o].y);
                        const __half2 hi = __floats2half2_rn(t[o].z, t[o].w);
                        uint2 pk;
                        pk.x = __builtin_bit_cast(uint32_t, lo);
                        pk.y = __builtin_bit_cast(uint32_t, hi);
                        wrow[o * 4] = pk;
                    }
                }
#pragma unroll
                for (int o = 0; o < NO; ++o) {
                    uu[o] = make_float4(t[o].x, t[o].y, t[o].z, t[o].w);
                    bnew[o] = b_lds[s * NO + o];   // vcum==0: logits = b_param
                }
            } else {
                // fp16 read: same thread wrote these exact bytes in pass 0
                const uint2* row = uhb + (size_t)s * UHROW + d4;
                uint2 pk[NO];
#pragma unroll
                for (int o = 0; o < NO; ++o) pk[o] = row[o * 4];
#pragma unroll
                for (int o = 0; o < NO; ++o) {
                    const float2 a = __half22float2(__builtin_bit_cast(__half2, pk[o].x));
                    const float2 b = __half22float2(__builtin_bit_cast(__half2, pk[o].y));
                    uu[o] = make_float4(a.x, a.y, b.x, b.y);
                }
                // agreement: dot(u, vcum) over D, reduced across the 4 d-lanes
#pragma unroll
                for (int o = 0; o < NO; ++o) {
                    const float4 vc = v_lds[o][d4];      // LDS broadcast
                    float p = uu[o].x * vc.x + uu[o].y * vc.y +
                              uu[o].z * vc.z + uu[o].w * vc.w;
                    p += __shfl_xor(p, 1);
                    p += __shfl_xor(p, 2);
                    bnew[o] = b_lds[s * NO + o] + p;
                }
            }

            // in-register softmax over O (redundant per lane; BW-bound)
            float mx = bnew[0];
#pragma unroll
            for (int o = 1; o < NO; ++o) mx = fmaxf(mx, bnew[o]);
            float ss = 0.f;
#pragma unroll
            for (int o = 0; o < NO; ++o) { bnew[o] = __expf(bnew[o] - mx); ss += bnew[o]; }
            const float inv = 1.f / ss;
#pragma unroll
            for (int o = 0; o < NO; ++o) {
                const float c = bnew[o] * inv;
                sacc[o].x += c * uu[o].x;
                sacc[o].y += c * uu[o].y;
                sacc[o].z += c * uu[o].z;
                sacc[o].w += c * uu[o].w;
            }
        }

        // reduce across the 16 row-groups of each wave (keep d4: masks 4..32)
#pragma unroll
        for (int o = 0; o < NO; ++o) {
#pragma unroll
            for (int mask = 4; mask <= 32; mask <<= 1) {
                sacc[o].x += __shfl_xor(sacc[o].x, mask);
                sacc[o].y += __shfl_xor(sacc[o].y, mask);
                sacc[o].z += __shfl_xor(sacc[o].z, mask);
                sacc[o].w += __shfl_xor(sacc[o].w, mask);
            }
        }
        if (lane < 4) {
#pragma unroll
            for (int o = 0; o < NO; ++o) sred[wave][o][lane] = sacc[o];
        }
        __syncthreads();

        if (tid < NO * 4) {                // 40 threads: (o, d-chunk)
            const int o = tid >> 2, dd = tid & 3;
            float4 sv = sred[0][o][dd];
#pragma unroll
            for (int w = 1; w < 8; ++w) {
                const float4 t = sred[w][o][dd];
                sv.x += t.x; sv.y += t.y; sv.z += t.z; sv.w += t.w;
            }
            // squash: v = s * (|s|^2/(1+|s|^2)) / (|s|+eps); norm over 4 d-lanes
            float q = sv.x * sv.x + sv.y * sv.y + sv.z * sv.z + sv.w * sv.w;
            q += __shfl_xor(q, 1);
            q += __shfl_xor(q, 2);
            const float len = sqrtf(q);
            const float f = (q / (1.f + q)) / (len + EPSV);
            const float4 vv = make_float4(sv.x * f, sv.y * f, sv.z * f, sv.w * f);
            const float4 c4 = v_lds[o][dd];            // vcum += v
            v_lds[o][dd] = make_float4(c4.x + vv.x, c4.y + vv.y,
                                       c4.z + vv.z, c4.w + vv.w);
            if (r == n - 1) {
                float* op = out + (size_t)bb * (NO * ND) + o * ND + dd * 4;
                atomicAdd(op + 0, vv.x);               // sum over g
                atomicAdd(op + 1, vv.y);
                atomicAdd(op + 2, vv.z);
                atomicAdd(op + 3, vv.w);
            }
        }
        __syncthreads();                   // vcum visible before next pass
    }
}

extern "C" void kernel_launch(void* const* d_in, const int* in_sizes, int n_in,
                              void* d_out, int out_size, void* d_ws, size_t ws_size,
                              hipStream_t stream) {
    const float* u   = (const float*)d_in[0];
    const float* bp  = (const float*)d_in[1];
    const int*   nit = (const int*)d_in[2];
    float* out = (float*)d_out;
    uint2* uh  = (uint2*)d_ws;             // fp16 copy of u: 94.4 MB

    (void)hipMemsetAsync(out, 0, (size_t)out_size * sizeof(float), stream);

    AgreementRouting_72988674228343_kernel<<<dim3(NB * NG), dim3(THREADS), 0, stream>>>(
        u, bp, nit, out, uh);
}